// Round 2
// baseline (228.505 us; speedup 1.0000x reference)
//
#include <hip/hip_runtime.h>
#include <math.h>

#define P_NODES 21
#define KNEG    5
#define DDIM    128
#define BATCH   1024
#define N_PAIRS 185                 // sum of window sizes for P=21, k=5
#define NP_TOT  (N_PAIRS * BATCH)   // 189440 = 740 * 256 exactly

struct Pairs { unsigned char pi[N_PAIRS]; unsigned char pj[N_PAIRS]; };

constexpr Pairs make_pairs() {
    Pairs p{};
    int n = 0;
    for (int i = 0; i < P_NODES; ++i) {
        int jlo = (i - KNEG > 0) ? i - KNEG : 0;
        int jhi = (i + KNEG < P_NODES) ? i + KNEG : P_NODES;
        for (int j = jlo; j < jhi; ++j) { p.pi[n] = (unsigned char)i; p.pj[n] = (unsigned char)j; ++n; }
    }
    return p;
}

__constant__ Pairs PAIRS = make_pairs();

// fast log-sigmoid: one v_exp + one v_log. |x| <= ~3 here, no overflow risk.
__device__ __forceinline__ float lsig(float x) {
    return -__logf(1.f + __expf(-x));
}

__device__ __forceinline__ float dot4(float4 a, float4 b) {
    return fmaf(a.x, b.x, fmaf(a.y, b.y, fmaf(a.z, b.z, a.w * b.w)));
}

__global__ __launch_bounds__(256) void mp2v_pair_kernel(
    const float* __restrict__ emb,
    const int*   __restrict__ path,
    const int*   __restrict__ neg,
    float*       __restrict__ out)
{
    const int g = blockIdx.x * 256 + threadIdx.x;   // one (pair,b) per lane; no tail
    const int b = g / N_PAIRS;
    const int p = g - b * N_PAIRS;

    const int* pb = path + b * P_NODES;
    const int  ci = pb[PAIRS.pi[p]];
    const int  cj = pb[PAIRS.pj[p]];

    const float4* C = (const float4*)(emb + (size_t)ci * DDIM);
    const float4* X = (const float4*)(emb + (size_t)cj * DDIM);

    const int* nb = neg + ((size_t)p * BATCH + b) * KNEG;
    const float4* N0 = (const float4*)(emb + (size_t)nb[0] * DDIM);
    const float4* N1 = (const float4*)(emb + (size_t)nb[1] * DDIM);
    const float4* N2 = (const float4*)(emb + (size_t)nb[2] * DDIM);
    const float4* N3 = (const float4*)(emb + (size_t)nb[3] * DDIM);
    const float4* N4 = (const float4*)(emb + (size_t)nb[4] * DDIM);

    float a0 = 0.f, a1 = 0.f, a2 = 0.f, a3 = 0.f, a4 = 0.f, a5 = 0.f;

    #pragma unroll 4
    for (int d = 0; d < DDIM / 4; ++d) {
        float4 c  = C[d];
        float4 x  = X[d];
        float4 n0 = N0[d];
        float4 n1 = N1[d];
        float4 n2 = N2[d];
        float4 n3 = N3[d];
        float4 n4 = N4[d];
        a0 += dot4(c, x);
        a1 += dot4(c, n0);
        a2 += dot4(c, n1);
        a3 += dot4(c, n2);
        a4 += dot4(c, n3);
        a5 += dot4(c, n4);
    }

    float loss = lsig(a0) + lsig(-a1) + lsig(-a2) + lsig(-a3) + lsig(-a4) + lsig(-a5);

    // full-wave butterfly reduce, one atomic per wave
    loss += __shfl_xor(loss, 32);
    loss += __shfl_xor(loss, 16);
    loss += __shfl_xor(loss, 8);
    loss += __shfl_xor(loss, 4);
    loss += __shfl_xor(loss, 2);
    loss += __shfl_xor(loss, 1);
    if ((threadIdx.x & 63) == 0)
        atomicAdd(out, loss * (-1.f / (float)BATCH));
}

extern "C" void kernel_launch(void* const* d_in, const int* in_sizes, int n_in,
                              void* d_out, int out_size, void* d_ws, size_t ws_size,
                              hipStream_t stream) {
    const float* emb  = (const float*)d_in[0];
    const int*   path = (const int*)d_in[1];
    const int*   neg  = (const int*)d_in[2];
    float*       out  = (float*)d_out;

    // d_out is poisoned once before timing and never re-poisoned: zero it each call.
    hipMemsetAsync(out, 0, sizeof(float), stream);

    mp2v_pair_kernel<<<NP_TOT / 256, 256, 0, stream>>>(emb, path, neg, out);
}

// Round 3
// 184.472 us; speedup vs baseline: 1.2387x; 1.2387x over previous
//
#include <hip/hip_runtime.h>
#include <math.h>

#define P_NODES 21
#define KNEG    5
#define DDIM    128
#define BATCH   1024
#define N_PAIRS 185                  // sum of window sizes for P=21, k=5
#define N_NEG   (N_PAIRS * KNEG)     // 925 neg dots per b
#define CHUNK   64                   // neg rows staged per iteration
#define NCHUNK  ((N_NEG + CHUNK - 1) / CHUNK)   // 15

struct Pairs { unsigned char pi[N_PAIRS]; unsigned char pj[N_PAIRS]; };

constexpr Pairs make_pairs() {
    Pairs p{};
    int n = 0;
    for (int i = 0; i < P_NODES; ++i) {
        int jlo = (i - KNEG > 0) ? i - KNEG : 0;
        int jhi = (i + KNEG < P_NODES) ? i + KNEG : P_NODES;
        for (int j = jlo; j < jhi; ++j) { p.pi[n] = (unsigned char)i; p.pj[n] = (unsigned char)j; ++n; }
    }
    return p;
}

__constant__ Pairs PAIRS = make_pairs();

// fast log-sigmoid: one v_exp + one v_log; |dot| is small here, no overflow risk.
__device__ __forceinline__ float lsig(float x) {
    return -__logf(1.f + __expf(-x));
}

__device__ __forceinline__ float dot4(float4 a, float4 b) {
    return fmaf(a.x, b.x, fmaf(a.y, b.y, fmaf(a.z, b.z, a.w * b.w)));
}

// One block per batch element b. Gathers are coalesced 512B-row loads staged
// through LDS; dot reductions are in-lane (4 lanes per dot, 2 shuffles).
// LDS rows stored ROTATED: row r, float4-chunk c lives at slot r*32+((c+r)&31)
// so 64 lanes reading their own rows at the same column spread across banks.
__global__ __launch_bounds__(256, 3) void mp2v_kernel(
    const float* __restrict__ emb,
    const int*   __restrict__ path,
    const int*   __restrict__ neg,
    float*       __restrict__ out)
{
    __shared__ float4 crow[P_NODES * 32];   // 10.5 KB, rotated
    __shared__ float4 nbuf[CHUNK * 32];     // 32 KB, rotated
    __shared__ int    nidx[N_NEG];          // 3.7 KB
    __shared__ int    pidx[P_NODES];
    __shared__ unsigned char spi[N_PAIRS];
    __shared__ unsigned char spj[N_PAIRS];
    __shared__ float  wsum[4];

    const int b = blockIdx.x;
    const int t = threadIdx.x;

    // ---- phase 0: index staging ----
    if (t < P_NODES) pidx[t] = path[b * P_NODES + t];
    if (t < N_PAIRS) { spi[t] = PAIRS.pi[t]; spj[t] = PAIRS.pj[t]; }
    for (int q = t; q < N_NEG; q += 256) {
        int p = q / KNEG;
        int k = q - p * KNEG;
        nidx[q] = neg[(size_t)p * (BATCH * KNEG) + b * KNEG + k];
    }
    __syncthreads();

    // ---- phase 1: stage the 21 c-rows (rotated) + issue chunk-0 loads ----
    for (int e = t; e < P_NODES * 32; e += 256) {
        int r = e >> 5, c = e & 31;
        float4 val = ((const float4*)(emb + (size_t)pidx[r] * DDIM))[c];
        crow[r * 32 + ((c + r) & 31)] = val;
    }
    float4 v[8];                           // chunk staging regs: 64 rows x 512B / 256 thr
    #pragma unroll
    for (int j = 0; j < 8; ++j) {
        int e = j * 256 + t;
        int r = e >> 5, c = e & 31;
        v[j] = ((const float4*)(emb + (size_t)nidx[r] * DDIM))[c];   // chunk 0: q=r<925
    }
    __syncthreads();                       // crow visible

    const int wv   = t >> 6;               // wave id 0..3
    const int L    = t & 63;
    const int rl16 = L & 15;               // row slot within wave
    const int u    = L >> 4;               // 0..3: which 32-float slice of the dot

    float acc = 0.f;

    // ---- phase 2: pos dots from crow (chunk-0 loads in flight) ----
    for (int rd = 0; rd < 3; ++rd) {
        int tq = rd * 64 + wv * 16 + rl16;  // uniform across the 4 partner lanes
        if (tq < N_PAIRS) {
            int ci = spi[tq];
            int cj = spj[tq];
            float part = 0.f;
            #pragma unroll
            for (int i = 0; i < 8; ++i) {
                int c = u * 8 + i;
                float4 a = crow[ci * 32 + ((c + ci) & 31)];
                float4 x = crow[cj * 32 + ((c + cj) & 31)];
                part += dot4(a, x);
            }
            part += __shfl_xor(part, 16);
            part += __shfl_xor(part, 32);
            acc += lsig(part);              // each dot counted 4x; scaled at the end
        }
    }

    // ---- neg loop: write staged chunk, prefetch next, compute ----
    for (int k = 0; k < NCHUNK; ++k) {
        __syncthreads();                    // nbuf free (previous compute done)
        #pragma unroll
        for (int j = 0; j < 8; ++j) {
            int e = j * 256 + t;
            int r = e >> 5, c = e & 31;
            nbuf[r * 32 + ((c + r) & 31)] = v[j];
        }
        if (k + 1 < NCHUNK) {
            #pragma unroll
            for (int j = 0; j < 8; ++j) {
                int e = j * 256 + t;
                int r = e >> 5, c = e & 31;
                int q = (k + 1) * CHUNK + r;
                int idx = nidx[q < N_NEG ? q : 0];    // tail: harmless row 0
                v[j] = ((const float4*)(emb + (size_t)idx * DDIM))[c];
            }
        }
        __syncthreads();                    // nbuf visible
        int r_loc = wv * 16 + rl16;
        int q = k * CHUNK + r_loc;          // uniform across the 4 partner lanes
        if (q < N_NEG) {
            int p  = q / KNEG;
            int ci = spi[p];
            float part = 0.f;
            #pragma unroll
            for (int i = 0; i < 8; ++i) {
                int c = u * 8 + i;
                float4 n = nbuf[r_loc * 32 + ((c + r_loc) & 31)];
                float4 a = crow[ci * 32 + ((c + ci) & 31)];
                part += dot4(n, a);
            }
            part += __shfl_xor(part, 16);
            part += __shfl_xor(part, 32);
            acc += lsig(-part);
        }
    }

    // ---- block reduce; every dot was counted 4x (u-duplicates) ----
    acc += __shfl_xor(acc, 32);
    acc += __shfl_xor(acc, 16);
    acc += __shfl_xor(acc, 8);
    acc += __shfl_xor(acc, 4);
    acc += __shfl_xor(acc, 2);
    acc += __shfl_xor(acc, 1);
    if (L == 0) wsum[wv] = acc;
    __syncthreads();
    if (t == 0) {
        float s = wsum[0] + wsum[1] + wsum[2] + wsum[3];
        atomicAdd(out, s * (-1.f / (4.f * (float)BATCH)));
    }
}

extern "C" void kernel_launch(void* const* d_in, const int* in_sizes, int n_in,
                              void* d_out, int out_size, void* d_ws, size_t ws_size,
                              hipStream_t stream) {
    const float* emb  = (const float*)d_in[0];
    const int*   path = (const int*)d_in[1];
    const int*   neg  = (const int*)d_in[2];
    float*       out  = (float*)d_out;

    // d_out is poisoned once before timing and never re-poisoned: zero it each call.
    hipMemsetAsync(out, 0, sizeof(float), stream);

    mp2v_kernel<<<BATCH, 256, 0, stream>>>(emb, path, neg, out);
}

// Round 4
// 146.947 us; speedup vs baseline: 1.5550x; 1.2554x over previous
//
#include <hip/hip_runtime.h>
#include <math.h>

#define P_NODES 21
#define KNEG    5
#define DDIM    128
#define BATCH   1024
#define N_PAIRS 185                  // pos tasks
#define N_NEG   (N_PAIRS * KNEG)     // 925 neg tasks
#define NTASK   (N_PAIRS + N_NEG)    // 1110 tasks per b
#define HALF_T  (NTASK / 2)          // 555 tasks per block (2 blocks per b)

struct Pairs { unsigned char pi[N_PAIRS]; unsigned char pj[N_PAIRS]; };

constexpr Pairs make_pairs() {
    Pairs p{};
    int n = 0;
    for (int i = 0; i < P_NODES; ++i) {
        int jlo = (i - KNEG > 0) ? i - KNEG : 0;
        int jhi = (i + KNEG < P_NODES) ? i + KNEG : P_NODES;
        for (int j = jlo; j < jhi; ++j) { p.pi[n] = (unsigned char)i; p.pj[n] = (unsigned char)j; ++n; }
    }
    return p;
}

__constant__ Pairs PAIRS = make_pairs();

// fast log-sigmoid: one v_exp + one v_log; dots are tiny here, no overflow risk.
__device__ __forceinline__ float lsig(float x) {
    return -__logf(1.f + __expf(-x));
}

__device__ __forceinline__ float dot4(float4 a, float4 b) {
    return fmaf(a.x, b.x, fmaf(a.y, b.y, fmaf(a.z, b.z, a.w * b.w)));
}

// 2 blocks per batch element b; each owns 555 of the 1110 dot tasks.
// 4 lanes per dot-row: lane m of a quad loads float4 cols m, m+4, ..., m+28
// (64B contiguous per quad per instr, row consumed immediately -> L1-friendly),
// dots against the LDS-resident rotated c-row, 2 shfl_xor reduce, all-lane lsig.
// NO barriers in the main loop -> latency hidden by ILP(8 loads) x TLP.
__global__ __launch_bounds__(256) void mp2v_kernel(
    const float* __restrict__ emb,
    const int*   __restrict__ path,
    const int*   __restrict__ neg,
    float*       __restrict__ out)
{
    __shared__ float4 crow[P_NODES * 32];     // 10.5 KB, slot rotated by row
    __shared__ int    nidx[N_NEG];            // 3.7 KB
    __shared__ int    pidx[P_NODES];
    __shared__ unsigned char spi[N_PAIRS];
    __shared__ unsigned char spj[N_PAIRS];

    const int blk  = blockIdx.x;
    const int b    = blk >> 1;
    const int q0   = (blk & 1) * HALF_T;      // 0 or 555
    const int q1   = q0 + HALF_T;
    const int t    = threadIdx.x;

    // ---- stage indices ----
    if (t < P_NODES) pidx[t] = path[b * P_NODES + t];
    if (t < N_PAIRS) { spi[t] = PAIRS.pi[t]; spj[t] = PAIRS.pj[t]; }
    for (int q = t; q < N_NEG; q += 256) {
        int p = (int)(((unsigned)q * 52429u) >> 18);   // q/5 exact for q < 2^18
        int k = q - p * KNEG;
        nidx[q] = neg[(size_t)p * (BATCH * KNEG) + b * KNEG + k];
    }
    __syncthreads();   // pidx ready

    // ---- stage the 21 c-rows, rotated: row r float4-slot c -> slot (c+r)&31 ----
    for (int e = t; e < P_NODES * 32; e += 256) {
        int r = e >> 5, c = e & 31;
        float4 val = ((const float4*)(emb + (size_t)pidx[r] * DDIM))[c];
        crow[r * 32 + ((c + r) & 31)] = val;
    }
    __syncthreads();   // crow + nidx ready; NO more barriers until the end

    const int w = t >> 6;          // wave 0..3
    const int l = t & 63;
    const int r = l >> 2;          // row-quad 0..15
    const int m = l & 3;           // float4 phase within row

    float acc = 0.f;

    for (int base = q0 + w * 16; base < q1; base += 64) {
        int q = base + r;
        if (q < q1) {
            float part = 0.f;
            float sgn;
            if (q < N_PAIRS) {
                // positive: both rows from LDS
                int ci = spi[q], cj = spj[q];
                #pragma unroll
                for (int i = 0; i < 8; ++i) {
                    int c = m + 4 * i;
                    float4 a = crow[ci * 32 + ((c + ci) & 31)];
                    float4 x = crow[cj * 32 + ((c + cj) & 31)];
                    part += dot4(a, x);
                }
                sgn = 1.f;
            } else {
                int qq = q - N_PAIRS;                                 // 0..924
                int p  = (int)(((unsigned)qq * 52429u) >> 18);        // qq/5
                int ci = spi[p];
                const float4* R = (const float4*)(emb + (size_t)nidx[qq] * DDIM);
                #pragma unroll
                for (int i = 0; i < 8; ++i) {
                    int c = m + 4 * i;
                    float4 n = R[c];
                    float4 a = crow[ci * 32 + ((c + ci) & 31)];
                    part += dot4(n, a);
                }
                sgn = -1.f;
            }
            // reduce across the 4-lane quad (masks 1,2 stay in-quad)
            part += __shfl_xor(part, 1);
            part += __shfl_xor(part, 2);
            acc += lsig(sgn * part);       // counted 4x (m duplicates)
        }
    }

    // ---- wave reduce, one atomic per wave; 4x duplication scaled out ----
    acc += __shfl_xor(acc, 32);
    acc += __shfl_xor(acc, 16);
    acc += __shfl_xor(acc, 8);
    acc += __shfl_xor(acc, 4);
    acc += __shfl_xor(acc, 2);
    acc += __shfl_xor(acc, 1);
    if (l == 0)
        atomicAdd(out, acc * (-1.f / (4.f * (float)BATCH)));
}

extern "C" void kernel_launch(void* const* d_in, const int* in_sizes, int n_in,
                              void* d_out, int out_size, void* d_ws, size_t ws_size,
                              hipStream_t stream) {
    const float* emb  = (const float*)d_in[0];
    const int*   path = (const int*)d_in[1];
    const int*   neg  = (const int*)d_in[2];
    float*       out  = (float*)d_out;

    // d_out is poisoned once before timing and never re-poisoned: zero it each call.
    hipMemsetAsync(out, 0, sizeof(float), stream);

    mp2v_kernel<<<BATCH * 2, 256, 0, stream>>>(emb, path, neg, out);
}